// Round 7
// baseline (412.672 us; speedup 1.0000x reference)
//
#include <hip/hip_runtime.h>
#include <stdint.h>

// SNN forward with STP/STDP, delays {1,2,3,5}, B=8 T=64 NI=256 N=512 NO=32 D=4.
// Persistent dataflow kernel: 256 blocks = 8 batches x 32 o-chunks (16 o's).
// ROUND-7: REGISTER PASS-THROUGH -- no LDS staging of records at all.
// Each record (slot,e) is consumed by exactly 16 threads = one load instruction
// of one wave, so LDS redistribution buys nothing. Each thread loads its 16
// synapses' records for step t+1 at the TOP of step t (full-step latency cover)
// into registers (vA/vB double-buffer, loop 2x-unrolled for static indexing),
// and VERIFIES the run-parity tag at consume (top of t+1, ~1.3 steps freshness
// slack; rare failure -> one agent reload). This deletes from the per-step
// serial chain: staging ds_writes, pre-barrier polls, their vmcnt drain, BAR2
// (red is double-buffered; red[p] reads@t precede BAR(t+1), rewrites@t+2 follow
// it), and acc's 16 ds_reads. ONE barrier per step. All record loads are
// agent-scope (uniform; no L1/L2 staleness cases).
// Cross-block recurrence: ONE packed 8B record per (t,b,n) = {syn_p, xbar|spike},
// agent-scope relaxed store; "unwritten" = RUN-PARITY TAG in syn_p's sign bit
// (syn_p >= 0 always since w_p > -1). Workspace re-poisoned every run (measured)
// => init always runs: parity-fill own rec slice + one done[]-tag grid barrier.
// Readout fused (r4-proven): per-step 16-bit spike ballot -> partial h2 ->
// f32 atomics -> batch-last block scans. Single dispatch, no memsets.

#define B  8
#define T  64
#define NI 256
#define NN 512
#define NO 32
#define DD 4

#define NBLK 256
#define TPB  512
#define OPB  16          // o's per block
#define EGR  32          // e-groups (tid>>4)
#define SPL  16          // synapses per lane (e = e_grp + 32*i)

#define RECB (B*NN*8)        // bytes per time-slot plane (32768)
#define REC_ELEMS (T*B*NN)   // packed 8B records
#define MAGIC  0x534E4E31u

// ctrl[] layout (u32): [0..7]=cnt per batch, [8]=gcnt, [9]=runpar, [10]=header,
//                      [16..271]=done[] per-block init tags
#define C_CNT   0
#define C_GCNT  8
#define C_PAR   9
#define C_HDR   10
#define C_DONE  16

__device__ __forceinline__ unsigned long long rec_load(const unsigned long long* p) {
    return __hip_atomic_load(p, __ATOMIC_RELAXED, __HIP_MEMORY_SCOPE_AGENT);
}
__device__ __forceinline__ void rec_store(unsigned long long* p, unsigned long long v) {
    __hip_atomic_store(p, v, __ATOMIC_RELAXED, __HIP_MEMORY_SCOPE_AGENT);
}
__device__ __forceinline__ unsigned ctrl_ld(const unsigned* p) {
    return __hip_atomic_load(p, __ATOMIC_RELAXED, __HIP_MEMORY_SCOPE_AGENT);
}
__device__ __forceinline__ void ctrl_st(unsigned* p, unsigned v) {
    __hip_atomic_store(p, v, __ATOMIC_RELAXED, __HIP_MEMORY_SCOPE_AGENT);
}
__device__ __forceinline__ bool unwritten(unsigned long long v, unsigned runpar) {
    return ((unsigned)v >> 31) != runpar;   // lo sign bit = run parity tag
}

// Raw barrier: drain LDS only (NOT vmcnt) -- record loads / publish store
// stay in flight across the barrier. Compiler still inserts counted vmcnt
// waits before any use of load results.
#define BAR_LDS() do {                                      \
    asm volatile("s_waitcnt lgkmcnt(0)" ::: "memory");      \
    __builtin_amdgcn_s_barrier();                           \
    asm volatile("" ::: "memory");                          \
} while (0)

__global__ __launch_bounds__(TPB, 2)
void snn_main(const float* __restrict__ inputs,
              const float* __restrict__ w,
              const float* __restrict__ w_in,
              const float* __restrict__ w_out,
              const float* __restrict__ dmap,
              const int*   __restrict__ delays,
              const float* __restrict__ w_signs,
              const float* __restrict__ p,
              const float* __restrict__ A_p,
              const float* __restrict__ A_d,
              unsigned long long* __restrict__ rec,
              float* __restrict__ h2buf,
              unsigned* __restrict__ ctrl,
              float* __restrict__ out)
{
    // LDS: no record planes. scratch aliases {prologue w_in tile} then
    // {readout h2_s + wout16_s}.
    __shared__ float scratch[NI*OPB];          // 16 KB
    __shared__ float  inp_s[T*OPB];            // per-block input-current slice
    __shared__ float  red[2][8*OPB];           // 8 wave partials, double-buffered
    __shared__ unsigned int spikebits_s[T];    // block's 16 neurons' spikes per step
    __shared__ int    last_s;

    const int tid     = threadIdx.x;
    const int bid     = blockIdx.x;
    const int b       = bid & 7;
    const int chunk   = bid >> 3;
    const int o_base  = chunk * OPB;
    const int o_local = tid & 15;
    const int e_grp   = tid >> 4;              // 0..31
    const int o       = o_base + o_local;

    // ---------------- init (runs every launch: ws is re-poisoned) -----------
    unsigned runpar;
    if (ctrl_ld(ctrl + C_HDR) != MAGIC) {
        {   // fill own rec slice: lo-sign=1 => "unwritten for run parity 0"
            unsigned long long* base = rec + (size_t)bid * (REC_ELEMS / NBLK);
            #pragma unroll
            for (int i = 0; i < REC_ELEMS / NBLK / TPB; ++i)
                rec_store(base + i*TPB + tid, 0x0000000080000000ull);
        }
        // zero own h2 slice
        if (tid < (B*T*NO) / NBLK)
            ctrl_st((unsigned*)h2buf + (size_t)bid * ((B*T*NO) / NBLK) + tid, 0u);
        if (bid == 0 && tid < 10) ctrl_st(ctrl + tid, 0u);  // cnt[8], gcnt, par
        __syncthreads();                    // drains vmcnt(0): all stores acked
        if (tid == 0) ctrl_st(ctrl + C_DONE + bid, MAGIC);
        // single grid arrival barrier: thread j (<256) watches done[j]
        if (tid < NBLK) {
            int guard = 0;
            while (ctrl_ld(ctrl + C_DONE + tid) != MAGIC) {
                __builtin_amdgcn_s_sleep(2);
                if (++guard > (1 << 20)) break;
            }
        }
        __syncthreads();
        runpar = 0u;
    } else {
        runpar = ctrl_ld(ctrl + C_PAR);     // ws persisted: fast path
    }

    // ---- publish slot 0 (zero record, parity-tagged) FIRST ----
    if (tid < OPB) {
        rec_store(rec + (size_t)(0*B + b)*NN + o_base + tid,
                  (unsigned long long)(runpar << 31));
    }
    if (tid == 0) spikebits_s[0] = 0u;

    // ---------------- per-lane synapse constants (registers) -----------------
    float wv[SPL], ap[SPL], ad[SPL], ws[SPL];
    int   voff[SPL];                  // byte offset: (b*NN+e)*8 - dly*RECB
    unsigned long long dpk = 0ull;    // packed 4-bit delay per synapse
    #pragma unroll
    for (int i = 0; i < SPL; ++i) {
        const int e = e_grp + EGR*i;
        wv[i] = w_signs[e] * fabsf(w[e*NN + o]);
        ap[i] = A_p[e*NN + o];
        ad[i] = A_d[e*NN + o];
        int d = 0;                    // argmax_d of one-hot dmap
        if (dmap[1*NN*NN + e*NN + o] != 0.0f) d = 1;
        if (dmap[2*NN*NN + e*NN + o] != 0.0f) d = 2;
        if (dmap[3*NN*NN + e*NN + o] != 0.0f) d = 3;
        const int dly = delays[d];    // in {1,2,3,5}
        ws[i]   = 1.0f;
        dpk    |= (unsigned long long)(unsigned)dly << (4*i);
        voff[i] = (b*NN + e)*8 - dly*RECB;
    }

    // ---------------- prologue: inp[b,t,o] slice = inputs @ w_in -------------
    {
        float* win = scratch;         // 4096 floats, prologue-only
        for (int k = tid; k < NI*OPB; k += TPB) {
            const int c = k >> 4, oo = k & 15;
            win[c*OPB + oo] = w_in[c*NN + o_base + oo];
        }
        __syncthreads();
        #pragma unroll
        for (int j = 0; j < T/EGR; ++j) {     // 2 rows per thread
            const int tj = e_grp*(T/EGR) + j;
            const float* inrow = inputs + (size_t)(b*T + tj)*NI;
            float a = 0.f;
            for (int c = 0; c < NI; ++c) a += inrow[c] * win[c*OPB + o_local];
            inp_s[tj*OPB + o_local] = a;
        }
        __syncthreads();
    }

    // neuron state, replicated across the 32 e_grp threads sharing an o
    float mem = 0.f, w_p = 0.f, x_bar = 0.f, u_pot = 0.f, u_dep = 0.f;
    const float p_o  = p[o];
    const float pd_o = (p_o < 0.f) ? 1.f : 0.f;

    // record registers: vc = verified-pending for step t (loaded during t-1),
    // vn = in-flight for step t+1. Double-buffered via 2x loop unroll.
    const float tz = __uint_as_float(runpar << 31);   // parity-tagged zero
    float2 vA[SPL], vB[SPL];
    #pragma unroll
    for (int i = 0; i < SPL; ++i) vA[i] = make_float2(tz, 0.f);

    auto STEP = [&](int t, float2 (&vc)[SPL], float2 (&vn)[SPL]) {
        const char* base1 = (const char*)rec + (size_t)(t+1)*RECB;

        // ---- A: issue ALL record loads for step t+1 (full-step cover).
        // d>=2 slots are >=1.3 steps post-publish; d=1 slot t has ~0.4-step
        // issue margin -- failures caught at next step's verify (rare reload).
        if (t + 1 < T) {
            if (t >= 4) {             // common path: every synapse active
                #pragma unroll
                for (int i = 0; i < SPL; ++i) {
                    const unsigned long long v =
                        rec_load((const unsigned long long*)(base1 + (long)voff[i]));
                    vn[i] = make_float2(__uint_as_float((unsigned)v),
                                        __uint_as_float((unsigned)(v >> 32)));
                }
            } else {                  // warmup: t+1 < dly => tagged zero
                #pragma unroll
                for (int i = 0; i < SPL; ++i) {
                    const int dly = (int)((dpk >> (4*i)) & 15ull);
                    float2 r = make_float2(tz, 0.f);
                    if (t + 1 >= dly) {
                        const unsigned long long v =
                            rec_load((const unsigned long long*)(base1 + (long)voff[i]));
                        r = make_float2(__uint_as_float((unsigned)v),
                                        __uint_as_float((unsigned)(v >> 32)));
                    }
                    vn[i] = r;
                }
            }
        }

        // ---- B: verify parity + acc (registers only; no LDS) ----
        const float spike = (mem > 1.0f) ? 1.0f : 0.0f;
        const float pg  = spike * fmaxf(u_pot, 0.f);   // STDP gates: pre-update u's
        const float udr = fmaxf(u_dep, 0.f);
        float acc = 0.f;
        #pragma unroll
        for (int i = 0; i < SPL; ++i) {
            unsigned lo = __float_as_uint(vc[i].x);
            if (__builtin_expect((lo >> 31) != runpar, 0)) {
                // stale sample: reload (peer published ~1.3 steps ago -> 1st hit)
                const unsigned long long* srcf = (const unsigned long long*)
                    ((const char*)rec + (size_t)t*RECB + (long)voff[i]);
                unsigned long long v; int guard = 0;
                do {
                    v = rec_load(srcf);
                    if (++guard > 2) __builtin_amdgcn_s_sleep(1);
                    if (guard > (1 << 18)) break;   // fail loud, not hung
                } while (unwritten(v, runpar));
                lo = (unsigned)v;
                vc[i].y = __uint_as_float((unsigned)(v >> 32));
            }
            const float x = __uint_as_float(lo & 0x7fffffffu);
            acc = fmaf(x, wv[i]*ws[i], acc);           // syn uses OLD w_stdp
        }

        // ---- C: reduce over e: xor-shuffles + 8 wave partials (dbuf'd) ----
        float a2 = acc + __shfl_xor(acc, 16);
        a2 += __shfl_xor(a2, 32);
        if ((tid & 63) < 16) red[t & 1][(tid >> 6)*16 + o_local] = a2;
        BAR_LDS();     // THE step barrier; vmem stays in flight
        float syn = 0.f;
        #pragma unroll
        for (int k = 0; k < 8; ++k) syn += red[t & 1][k*16 + o_local];

        // ---- E: state updates (reference order; u's use pre-update mem) ----
        const float wp_new = 0.85f*w_p + spike * p_o * (1.f + pd_o*w_p);
        const float xb_new = 0.95f*x_bar + 0.05f*spike;
        u_pot = 0.95f*u_pot + 0.05f*mem;
        u_dep = 0.95f*u_dep + 0.05f*mem;
        mem   = 0.9f*mem + inp_s[t*OPB + o_local] + syn - spike;
        w_p   = wp_new;
        x_bar = xb_new;

        // ---- F: publish record for step t+1 (pre-update values of t+1) ----
        if (t + 1 < T && tid < OPB) {
            const float spike1 = (mem > 1.0f) ? 1.0f : 0.0f;
            const float sp = spike1 * (1.f + w_p);     // >= 0: sign bit free
            const unsigned int xu = __float_as_uint(x_bar) | (spike1 != 0.f ? 0x80000000u : 0u);
            const unsigned int lo = __float_as_uint(sp) | (runpar << 31);
            const unsigned long long pk = ((unsigned long long)xu << 32) | lo;
            rec_store(rec + (size_t)((t+1)*B + b)*NN + o_base + tid, pk);
            const unsigned long long bal = __ballot(spike1 != 0.0f);
            if (tid == 0) spikebits_s[t+1] = (unsigned int)bal;
        }

        // ---- G: STDP ws-update (covers publish visibility; pre-update gates) --
        #pragma unroll
        for (int i = 0; i < SPL; ++i) {
            const unsigned int xu = __float_as_uint(vc[i].y);
            const float dep = ((int)xu < 0) ? ad[i]*udr : 0.f;  // X in sign bit
            const float pot = (ap[i]*pg) * fabsf(vc[i].y);
            ws[i] = fminf(fmaxf(ws[i] + pot - dep, 0.f), 2.f);
        }
        // no second barrier: red is double-buffered; reads of red[p]@t precede
        // BAR(t+1), rewrites@t+2 follow it (barrier transitivity).
    };

    for (int t = 0; t < T; t += 2) {
        STEP(t,     vA, vB);
        STEP(t + 1, vB, vA);
    }

    // ================= fused readout =================
    __syncthreads();   // spikebits_s complete block-wide
    float* wout16_s = scratch;             // [OPB*NO]
    float* h2_s     = scratch + OPB*NO;    // [T*NO]
    for (int k = tid; k < OPB*NO; k += TPB)
        wout16_s[k] = w_out[(o_base + (k >> 5))*NO + (k & 31)];
    __syncthreads();

    const int g  = tid >> 5;        // 0..15 -> t-sixteenth
    const int oo = tid & 31;        // output index
    #pragma unroll
    for (int j = 0; j < 4; ++j) {
        const int t = g*4 + j;
        const unsigned int bits = spikebits_s[t];
        float a = 0.f;
        #pragma unroll
        for (int i = 0; i < OPB; ++i)
            if (bits & (1u << i)) a += wout16_s[i*NO + oo];
        if (a != 0.f) atomicAdd(h2buf + ((size_t)b*T + t)*NO + oo, a);
    }
    __threadfence();                 // make our h2 atomics visible before arrival
    __syncthreads();
    if (tid == 0) last_s = (atomicAdd(ctrl + C_CNT + b, 1u) == 31u) ? 1 : 0;
    __syncthreads();

    if (last_s) {
        // last-arriving block of batch b: gather h2, leaky scan, reset h2
        __threadfence();
        #pragma unroll
        for (int j = 0; j < 4; ++j) {
            const int t = g*4 + j;
            h2_s[t*NO + oo] = __hip_atomic_load(h2buf + ((size_t)b*T + t)*NO + oo,
                                                __ATOMIC_RELAXED, __HIP_MEMORY_SCOPE_AGENT);
        }
        __syncthreads();
        #pragma unroll
        for (int j = 0; j < 4; ++j) {   // zero-after-read (persisted-ws path safety)
            const int t = g*4 + j;
            __hip_atomic_store((unsigned*)(h2buf + ((size_t)b*T + t)*NO + oo), 0u,
                               __ATOMIC_RELAXED, __HIP_MEMORY_SCOPE_AGENT);
        }
        if (tid < NO) {
            float st = 0.f;
            for (int t = 0; t < T; ++t) {
                st = 0.9f*st + h2_s[t*NO + tid];
                out[((size_t)b*T + t)*NO + tid] = st;
            }
        }
    }

    // ---- global arrival: the 256th block flips run state for the next launch ----
    if (tid == 0) {
        const unsigned gar = __hip_atomic_fetch_add(ctrl + C_GCNT, 1u,
                                                    __ATOMIC_ACQ_REL, __HIP_MEMORY_SCOPE_AGENT);
        if (gar == NBLK - 1) {
            for (int i = 0; i < 8; ++i) ctrl_st(ctrl + C_CNT + i, 0u);
            ctrl_st(ctrl + C_GCNT, 0u);
            ctrl_st(ctrl + C_PAR, runpar ^ 1u);
            ctrl_st(ctrl + C_HDR, MAGIC);
        }
    }
}

extern "C" void kernel_launch(void* const* d_in, const int* in_sizes, int n_in,
                              void* d_out, int out_size, void* d_ws, size_t ws_size,
                              hipStream_t stream)
{
    const float* inputs  = (const float*)d_in[0];
    const float* w       = (const float*)d_in[1];
    const float* w_in    = (const float*)d_in[2];
    const float* w_out   = (const float*)d_in[3];
    const float* dmap    = (const float*)d_in[4];
    const int*   delays  = (const int*)  d_in[5];
    const float* w_signs = (const float*)d_in[6];
    const float* p       = (const float*)d_in[7];
    const float* A_p     = (const float*)d_in[8];
    const float* A_d     = (const float*)d_in[9];

    char* wsb = (char*)d_ws;
    unsigned long long* rec = (unsigned long long*)wsb;            // 2 MB packed records
    float* h2buf = (float*)(wsb + (size_t)REC_ELEMS*8);            // 64 KB
    unsigned* ctrl = (unsigned*)(wsb + (size_t)REC_ELEMS*8 + (size_t)B*T*NO*4);

    // Single dispatch: init (parity fill + one grid tag-barrier) runs in-kernel.
    hipLaunchKernelGGL(snn_main, dim3(NBLK), dim3(TPB), 0, stream,
                       inputs, w, w_in, w_out, dmap, delays, w_signs, p, A_p, A_d,
                       rec, h2buf, ctrl, (float*)d_out);
}

// Round 9
// 224.024 us; speedup vs baseline: 1.8421x; 1.8421x over previous
//
#include <hip/hip_runtime.h>
#include <stdint.h>

// SNN forward with STP/STDP, delays {1,2,3,5}, B=8 T=64 NI=256 N=512 NO=32 D=4.
// Persistent dataflow kernel: 256 blocks = 8 batches x 32 o-chunks (16 o's).
// SESSION OPTIMUM (round-4 structure, reverted after r5/r6/r7 regressions):
//  * 512 threads/block = 8 waves/CU = 2 waves/SIMD -- measured sweet spot
//    (1/SIMD: 3.3us/step; 2/SIMD: 2.4; 4/SIMD: 2.7). 32 e-groups x 16 syn/lane.
//  * two lgkmcnt-only barriers/step; prefetch at top (full-step latency cover),
//    LDS-staged records (dedup: 4 loads/thread feed 16 consumers each),
//    publish EARLY (decoupled from staging polls), STDP loop covers publish
//    visibility. Register pass-through (r7) and polls-before-barrier (r5)
//    are both measured-worse.
// Cross-block recurrence: ONE packed 8B record per (t,b,n) = {syn_p, xbar|spike},
// agent-scope relaxed atomic store (single store); "unwritten" = RUN-PARITY TAG
// in syn_p's sign bit (syn_p >= 0 always). Consumers: delay-1 plane prefetched
// with AGENT loads (first-touch, no cache benefit); delay>=2 planes with PLAIN
// loads (L1/L2-cacheable: each slot is read 4x per block, reads 2-4 hit cache.
// Safe: records are write-once per run, dispatch-acquire invalidates caches at
// launch, so stale plain data can only be wrong-parity -> agent-scope poll
// fallback). Workspace re-poisoned every run (measured) => init always runs:
// parity-fill own rec slice + one done[]-tag grid barrier.
// Readout fused: per-step 16-bit spike ballot -> partial h2 -> f32 atomics ->
// batch-last block scans. Single dispatch, no memsets.

#define B  8
#define T  64
#define NI 256
#define NN 512
#define NO 32
#define DD 4

#define NBLK 256
#define TPB  512
#define OPB  16          // o's per block
#define EGR  32          // e-groups (tid>>4)
#define SPL  16          // synapses per lane (e = e_grp + 32*i)
#define EPAD 516         // padded per-d LDS plane stride (float2 elems)

#define REC_ELEMS (T*B*NN)   // packed 8B records
#define MAGIC  0x534E4E31u

// ctrl[] layout (u32): [0..7]=cnt per batch, [8]=gcnt, [9]=runpar, [10]=header,
//                      [16..271]=done[] per-block init tags
#define C_CNT   0
#define C_GCNT  8
#define C_PAR   9
#define C_HDR   10
#define C_DONE  16

__device__ __forceinline__ unsigned long long rec_load(const unsigned long long* p) {
    return __hip_atomic_load(p, __ATOMIC_RELAXED, __HIP_MEMORY_SCOPE_AGENT);
}
__device__ __forceinline__ unsigned long long rec_load_plain(const unsigned long long* p) {
    return *p;   // L1/L2-cacheable; write-once data => stale == wrong parity
}
__device__ __forceinline__ void rec_store(unsigned long long* p, unsigned long long v) {
    __hip_atomic_store(p, v, __ATOMIC_RELAXED, __HIP_MEMORY_SCOPE_AGENT);
}
__device__ __forceinline__ unsigned ctrl_ld(const unsigned* p) {
    return __hip_atomic_load(p, __ATOMIC_RELAXED, __HIP_MEMORY_SCOPE_AGENT);
}
__device__ __forceinline__ void ctrl_st(unsigned* p, unsigned v) {
    __hip_atomic_store(p, v, __ATOMIC_RELAXED, __HIP_MEMORY_SCOPE_AGENT);
}
__device__ __forceinline__ bool unwritten(unsigned long long v, unsigned runpar) {
    return ((unsigned)v >> 31) != runpar;   // lo sign bit = run parity tag
}
__device__ __forceinline__ unsigned long long poll_written(
        const unsigned long long* src, unsigned long long v, unsigned runpar) {
    int guard = 0;
    while (unwritten(v, runpar)) {
        if (guard >= 2) __builtin_amdgcn_s_sleep(1);   // fast-retry first
        v = rec_load(src);                             // authoritative (agent)
        if (++guard > (1 << 18)) break;                // fail loud, not hung
    }
    return v;
}

// Raw barrier: drain LDS only (NOT vmcnt) -- prefetch loads / publish store
// stay in flight across the barrier. Compiler still inserts counted vmcnt
// waits before any use of load results.
#define BAR_LDS() do {                                      \
    asm volatile("s_waitcnt lgkmcnt(0)" ::: "memory");      \
    __builtin_amdgcn_s_barrier();                           \
    asm volatile("" ::: "memory");                          \
} while (0)

__global__ __launch_bounds__(TPB, 2)
void snn_main(const float* __restrict__ inputs,
              const float* __restrict__ w,
              const float* __restrict__ w_in,
              const float* __restrict__ w_out,
              const float* __restrict__ dmap,
              const int*   __restrict__ delays,
              const float* __restrict__ w_signs,
              const float* __restrict__ p,
              const float* __restrict__ A_p,
              const float* __restrict__ A_d,
              unsigned long long* __restrict__ rec,
              float* __restrict__ h2buf,
              unsigned* __restrict__ ctrl,
              float* __restrict__ out)
{
    // LDS: sxq[d][e] padded planes = {syn_p, xbar|spikebit}. 16512 B.
    __shared__ float2 sxq[DD*EPAD];
    __shared__ float  inp_s[T*OPB];        // per-block input-current slice
    __shared__ float  red[8*OPB];          // 8 wave partials for the e-reduction
    __shared__ unsigned int spikebits_s[T];// this block's 16 neurons' spikes per step
    __shared__ float  wout16_s[OPB*NO];    // w_out rows of this block's neurons
    __shared__ float  h2_s[T*NO];          // last-block scan staging
    __shared__ int    last_s;

    const int tid     = threadIdx.x;
    const int bid     = blockIdx.x;
    const int b       = bid & 7;           // round-robin => batch b lives on XCD b
    const int chunk   = bid >> 3;
    const int o_base  = chunk * OPB;
    const int o_local = tid & 15;
    const int e_grp   = tid >> 4;          // 0..31
    const int o       = o_base + o_local;

    // ---------------- init (runs every launch: ws is re-poisoned) -----------
    unsigned runpar;
    if (ctrl_ld(ctrl + C_HDR) != MAGIC) {
        // fill own rec slice: lo-sign=1 => "unwritten for run parity 0"
        {
            unsigned long long* base = rec + (size_t)bid * (REC_ELEMS / NBLK);
            #pragma unroll
            for (int i = 0; i < REC_ELEMS / NBLK / TPB; ++i)
                rec_store(base + i*TPB + tid, 0x0000000080000000ull);
        }
        // zero own h2 slice
        {
            unsigned* hb = (unsigned*)h2buf + (size_t)bid * ((B*T*NO) / NBLK);
            if (tid < (B*T*NO) / NBLK) ctrl_st(hb + tid, 0u);
        }
        if (bid == 0 && tid < 10) ctrl_st(ctrl + tid, 0u);  // cnt[8], gcnt, par
        __syncthreads();                    // drains vmcnt(0): all stores acked
        if (tid == 0) ctrl_st(ctrl + C_DONE + bid, MAGIC);
        // single grid arrival barrier: thread j watches done[j]
        if (tid < NBLK) {
            int guard = 0;
            while (ctrl_ld(ctrl + C_DONE + tid) != MAGIC) {
                __builtin_amdgcn_s_sleep(2);
                if (++guard > (1 << 20)) break;
            }
        }
        __syncthreads();
        runpar = 0u;
    } else {
        runpar = ctrl_ld(ctrl + C_PAR);     // ws persisted: fast path
    }

    // ---- publish slot 0 (zero record, parity-tagged) FIRST ----
    if (tid < OPB) {
        rec_store(rec + (size_t)(0*B + b)*NN + o_base + tid,
                  (unsigned long long)(runpar << 31));
    }
    if (tid == 0) spikebits_s[0] = 0u;

    // ---------------- per-lane synapse constants (registers) -----------------
    float wv[SPL], ap[SPL], ad[SPL], ws[SPL];
    int   laddr[SPL];                 // precomputed LDS byte offset of (d,e) slot
    #pragma unroll
    for (int i = 0; i < SPL; ++i) {
        const int e = e_grp + EGR*i;
        wv[i] = w_signs[e] * fabsf(w[e*NN + o]);
        ap[i] = A_p[e*NN + o];
        ad[i] = A_d[e*NN + o];
        int d = 0;                    // argmax_d of one-hot dmap
        if (dmap[1*NN*NN + e*NN + o] != 0.0f) d = 1;
        if (dmap[2*NN*NN + e*NN + o] != 0.0f) d = 2;
        if (dmap[3*NN*NN + e*NN + o] != 0.0f) d = 3;
        ws[i]    = 1.0f;
        laddr[i] = (d*EPAD + e) * 8;
    }
    int del[DD];
    #pragma unroll
    for (int d = 0; d < DD; ++d) del[d] = delays[d];

    // ---------------- prologue: inp[b,t,o] slice = inputs @ w_in -------------
    {
        float* win = (float*)sxq;     // 4096 floats alias, prologue-only
        #pragma unroll
        for (int q = 0; q < NI*OPB/TPB; ++q) {
            const int k = q*TPB + tid;
            const int c = k >> 4, oo = k & 15;
            win[c*OPB + oo] = w_in[c*NN + o_base + oo];
        }
        __syncthreads();
        #pragma unroll
        for (int j = 0; j < T/EGR; ++j) {     // 2 rows per thread
            const int tj = e_grp*(T/EGR) + j;
            const float* inrow = inputs + (size_t)(b*T + tj)*NI;
            float a = 0.f;
            for (int c = 0; c < NI; ++c) a += inrow[c] * win[c*OPB + o_local];
            inp_s[tj*OPB + o_local] = a;
        }
        __syncthreads();
    }

    // zero-fill sxq for step 0 (all delays > 0 => all gathered slots are zero)
    #pragma unroll
    for (int d = 0; d < DD; ++d)
        sxq[d*EPAD + tid] = make_float2(0.f, 0.f);
    __syncthreads();

    // neuron state, replicated across the 32 e_grp threads sharing an o
    float mem = 0.f, w_p = 0.f, x_bar = 0.f, u_pot = 0.f, u_dep = 0.f;
    const float p_o  = p[o];
    const float pd_o = (p_o < 0.f) ? 1.f : 0.f;

    unsigned long long pf[DD];        // prefetched records for next step (ALL d)
    const int stage_ord[DD] = {1, 2, 3, 0};   // delay-1 plane (del[0]) staged LAST

    for (int t = 0; t < T; ++t) {
        // ---- prefetch ALL delay planes for step t+1 (in flight across barriers).
        // delay-1 = agent (first-touch); delay>=2 = plain (L1/L2 re-read hit) ----
        if (t + 1 < T) {
            #pragma unroll
            for (int d = 0; d < DD; ++d) {
                if (t + 1 >= del[d]) {
                    const int s = (t + 1 - del[d]) & 63;
                    const unsigned long long* src = rec + (size_t)(s*B + b)*NN + tid;
                    pf[d] = (del[d] == 1) ? rec_load(src) : rec_load_plain(src);
                }
            }
        }

        // ---- acc-only loop: 16 synapses/lane, keep staged v[] in registers ----
        const float spike = (mem > 1.0f) ? 1.0f : 0.0f;
        const float pg  = spike * fmaxf(u_pot, 0.f);   // STDP gates: pre-update u's
        const float udr = fmaxf(u_dep, 0.f);
        float2 v[SPL];
        float acc = 0.f;
        #pragma unroll
        for (int i = 0; i < SPL; ++i) {
            v[i] = *(const float2*)((const char*)sxq + laddr[i]);
            acc = fmaf(v[i].x, wv[i]*ws[i], acc);      // syn uses OLD w_stdp
        }
        // reduce over e: intra-wave xor-shuffles (4 e_grps/wave), 8 wave partials
        float a2 = acc + __shfl_xor(acc, 16);
        a2 += __shfl_xor(a2, 32);
        if ((tid & 63) < 16) red[(tid >> 6)*16 + o_local] = a2;
        BAR_LDS();         // B2: red visible block-wide; vmem stays in flight
        float syn = 0.f;
        #pragma unroll
        for (int k = 0; k < 8; ++k) syn += red[k*16 + o_local];

        // ---- state updates (reference order; u's use pre-update mem) ----
        const float wp_new = 0.85f*w_p + spike * p_o * (1.f + pd_o*w_p);
        const float xb_new = 0.95f*x_bar + 0.05f*spike;
        u_pot = 0.95f*u_pot + 0.05f*mem;
        u_dep = 0.95f*u_dep + 0.05f*mem;
        mem   = 0.9f*mem + inp_s[t*OPB + o_local] + syn - spike;
        w_p   = wp_new;
        x_bar = xb_new;

        // ---- publish record for step t+1 EARLY (before STDP loop) ----
        if (t + 1 < T && tid < OPB) {
            const float spike1 = (mem > 1.0f) ? 1.0f : 0.0f;
            const float sp = spike1 * (1.f + w_p);     // >= 0: sign bit free
            const unsigned int xu = __float_as_uint(x_bar) | (spike1 != 0.f ? 0x80000000u : 0u);
            const unsigned int lo = __float_as_uint(sp) | (runpar << 31);
            const unsigned long long pk = ((unsigned long long)xu << 32) | lo;
            rec_store(rec + (size_t)((t+1)*B + b)*NN + o_base + tid, pk);
            const unsigned long long bal = __ballot(spike1 != 0.0f);
            if (tid == 0) spikebits_s[t+1] = (unsigned int)bal;
        }

        // ---- STDP ws-update (covers publish visibility; uses pre-update gates) --
        #pragma unroll
        for (int i = 0; i < SPL; ++i) {
            const unsigned int xu = __float_as_uint(v[i].y);
            const float dep = ((int)xu < 0) ? ad[i]*udr : 0.f;  // X in sign bit
            const float pot = (ap[i]*pg) * fabsf(v[i].y);
            ws[i] = fminf(fmaxf(ws[i] + pot - dep, 0.f), 2.f);
        }

        // ---- stage step t+1 into LDS from prefetch; delay-1 plane LAST ----
        if (t + 1 < T) {
            #pragma unroll
            for (int j = 0; j < DD; ++j) {
                const int d = stage_ord[j];
                unsigned long long v0 = (unsigned long long)(runpar << 31);
                if (t + 1 >= del[d]) {
                    const int s = (t + 1 - del[d]) & 63;
                    const unsigned long long* src = rec + (size_t)(s*B + b)*NN + tid;
                    v0 = poll_written(src, pf[d], runpar);
                }
                sxq[d*EPAD + tid] =
                    make_float2(__uint_as_float((unsigned)v0 & 0x7fffffffu),
                                __uint_as_float((unsigned)(v0 >> 32)));
            }
        }
        BAR_LDS();         // END: sxq staged for t+1; red reads of t done
    }

    // ================= fused readout =================
    // (1) per-block partial h2 over its own 16 neurons, from the LDS spike bitmap
    if (tid < OPB*NO) wout16_s[tid] = w_out[(o_base + (tid >> 5))*NO + (tid & 31)];
    __syncthreads();

    const int g  = tid >> 5;        // 0..15 -> t-sixteenth
    const int oo = tid & 31;        // output index
    #pragma unroll
    for (int j = 0; j < 4; ++j) {
        const int t = g*4 + j;
        const unsigned int bits = spikebits_s[t];
        float a = 0.f;
        #pragma unroll
        for (int i = 0; i < OPB; ++i)
            if (bits & (1u << i)) a += wout16_s[i*NO + oo];
        if (a != 0.f) atomicAdd(h2buf + ((size_t)b*T + t)*NO + oo, a);
    }
    __threadfence();                 // make our h2 atomics visible before arrival
    __syncthreads();
    if (tid == 0) last_s = (atomicAdd(ctrl + C_CNT + b, 1u) == 31u) ? 1 : 0;
    __syncthreads();

    if (last_s) {
        // (2) last-arriving block of batch b: gather h2, leaky scan
        __threadfence();
        #pragma unroll
        for (int j = 0; j < 4; ++j) {
            const int t = g*4 + j;
            h2_s[t*NO + oo] = __hip_atomic_load(h2buf + ((size_t)b*T + t)*NO + oo,
                                                __ATOMIC_RELAXED, __HIP_MEMORY_SCOPE_AGENT);
        }
        __syncthreads();
        if (tid < NO) {
            float st = 0.f;
            for (int t = 0; t < T; ++t) {
                st = 0.9f*st + h2_s[t*NO + tid];
                out[((size_t)b*T + t)*NO + tid] = st;
            }
        }
    }

    // ---- global arrival: the 256th block flips run state for the next launch ----
    if (tid == 0) {
        const unsigned gar = __hip_atomic_fetch_add(ctrl + C_GCNT, 1u,
                                                    __ATOMIC_ACQ_REL, __HIP_MEMORY_SCOPE_AGENT);
        if (gar == NBLK - 1) {
            for (int i = 0; i < 8; ++i) ctrl_st(ctrl + C_CNT + i, 0u);
            ctrl_st(ctrl + C_GCNT, 0u);
            ctrl_st(ctrl + C_PAR, runpar ^ 1u);
            ctrl_st(ctrl + C_HDR, MAGIC);
        }
    }
}

extern "C" void kernel_launch(void* const* d_in, const int* in_sizes, int n_in,
                              void* d_out, int out_size, void* d_ws, size_t ws_size,
                              hipStream_t stream)
{
    const float* inputs  = (const float*)d_in[0];
    const float* w       = (const float*)d_in[1];
    const float* w_in    = (const float*)d_in[2];
    const float* w_out   = (const float*)d_in[3];
    const float* dmap    = (const float*)d_in[4];
    const int*   delays  = (const int*)  d_in[5];
    const float* w_signs = (const float*)d_in[6];
    const float* p       = (const float*)d_in[7];
    const float* A_p     = (const float*)d_in[8];
    const float* A_d     = (const float*)d_in[9];

    char* wsb = (char*)d_ws;
    unsigned long long* rec = (unsigned long long*)wsb;            // 2 MB packed records
    float* h2buf = (float*)(wsb + (size_t)REC_ELEMS*8);            // 64 KB
    unsigned* ctrl = (unsigned*)(wsb + (size_t)REC_ELEMS*8 + (size_t)B*T*NO*4);

    // Single dispatch: init (parity fill + one grid tag-barrier) runs in-kernel.
    hipLaunchKernelGGL(snn_main, dim3(NBLK), dim3(TPB), 0, stream,
                       inputs, w, w_in, w_out, dmap, delays, w_signs, p, A_p, A_d,
                       rec, h2buf, ctrl, (float*)d_out);
}